// Round 1
// baseline (1662.418 us; speedup 1.0000x reference)
//
#include <hip/hip_runtime.h>
#include <stdint.h>

#define HD 4096
#define TD 8192

typedef unsigned short u16;
typedef unsigned int u32;
typedef __bf16 bf16x8 __attribute__((ext_vector_type(8)));
typedef float f32x4 __attribute__((ext_vector_type(4)));

// async global->LDS, 16B per lane; LDS dest is wave-uniform base + lane*16,
// so lane l's global chunk must map to ldsbase + l*16 (layouts below do).
#define GL16(gp, lp) __builtin_amdgcn_global_load_lds( \
    (__attribute__((address_space(1))) void*)(void*)(uintptr_t)(gp), \
    (__attribute__((address_space(3))) void*)(lp), 16, 0, 0)

// ---------- NVFP4 quantization helpers ----------

// Round f (>=0) to nearest e4m3fn value (RTNE), returned as the decoded float.
// step = 2^(e-3) for f's binade e (clamped at -6 for the subnormal region,
// giving the 2^-9 subnormal quantum). (f + 2^23*step) - 2^23*step performs
// exact RTNE onto multiples of step.
__device__ __forceinline__ float e4m3_rtne(float f) {
  if (f <= 0.0f) return 0.0f;
  unsigned u = __float_as_uint(f);
  int e = (int)((u >> 23) & 0xff) - 127;
  if (e < -6) e = -6;
  float C = __uint_as_float((unsigned)(e + 147) << 23);  // 2^(e+20)
  float r = (f + C) - C;
  return fminf(r, 448.0f);
}

// Quantize 16 fp32 values (one NVFP4 block) with global scale g; write 16
// dequantized-(x*g-scale) values as bf16 bits (exact: <=6 significand bits).
// e2m1 ladder matches searchsorted(MID, a, side='right'): a==mid -> upper.
__device__ __forceinline__ void quant_store16(const float v[16], float g, u16* dst) {
  float amax = 0.0f;
#pragma unroll
  for (int j = 0; j < 16; ++j) amax = fmaxf(amax, fabsf(v[j]));
  float s = e4m3_rtne(amax * g / 6.0f);
  u32 out[8];
  if (s > 0.0f) {
    const float m1 = 0.25f * s, m2 = 0.75f * s, m3 = 1.25f * s, m4 = 1.75f * s;
    const float m5 = 2.5f * s, m6 = 3.5f * s, m7 = 5.0f * s;
#pragma unroll
    for (int p = 0; p < 8; ++p) {
      u16 b[2];
#pragma unroll
      for (int h = 0; h < 2; ++h) {
        float t = v[2 * p + h] * g;
        float u = fabsf(t);
        float q = (u < m4) ? ((u < m2) ? ((u < m1) ? 0.0f : 0.5f)
                                       : ((u < m3) ? 1.0f : 1.5f))
                           : ((u < m6) ? ((u < m5) ? 2.0f : 3.0f)
                                       : ((u < m7) ? 4.0f : 6.0f));
        float val = copysignf(q * s, t);
        b[h] = (u16)(__float_as_uint(val) >> 16);  // exact bf16 truncation
      }
      out[p] = (u32)b[0] | ((u32)b[1] << 16);
    }
  } else {
#pragma unroll
    for (int p = 0; p < 8; ++p) out[p] = 0u;
  }
  uint4* d4 = (uint4*)dst;
  d4[0] = make_uint4(out[0], out[1], out[2], out[3]);
  d4[1] = make_uint4(out[4], out[5], out[6], out[7]);
}

__device__ __forceinline__ float block_sum256(float v) {
#pragma unroll
  for (int off = 32; off > 0; off >>= 1) v += __shfl_down(v, off, 64);
  __shared__ float red[4];
  int tid = threadIdx.x;
  if ((tid & 63) == 0) red[tid >> 6] = v;
  __syncthreads();
  return (red[0] + red[1]) + (red[2] + red[3]);
}

// ---------- elementwise / norm kernels (one block per row, 16 elem/thread) ----------

__global__ __launch_bounds__(256) void k_relu_norm_quant(
    const float* __restrict__ hs, const float* __restrict__ nw,
    const float* __restrict__ agp, float* __restrict__ resid,
    u16* __restrict__ yq) {
  const int row = blockIdx.x, tid = threadIdx.x;
  const size_t base = (size_t)row * HD + tid * 16;
  float v[16];
#pragma unroll
  for (int j = 0; j < 4; ++j) ((float4*)v)[j] = ((const float4*)(hs + base))[j];
  float ss = 0.0f;
#pragma unroll
  for (int j = 0; j < 16; ++j) {
    v[j] = fmaxf(v[j], 0.0f);
    ss += v[j] * v[j];
  }
#pragma unroll
  for (int j = 0; j < 4; ++j) ((float4*)(resid + base))[j] = ((float4*)v)[j];
  float tot = block_sum256(ss);
  float rs = 1.0f / sqrtf(tot * (1.0f / HD) + 1e-6f);
  const float* nwp = nw + tid * 16;  // norm_w[0]
  float y[16];
#pragma unroll
  for (int j = 0; j < 16; ++j) y[j] = v[j] * rs * nwp[j];
  quant_store16(y, agp[0], yq + base);
}

__global__ __launch_bounds__(256) void k_norm_quant(
    const float* __restrict__ resid, const float* __restrict__ nw,
    const float* __restrict__ agp, int li, u16* __restrict__ yq) {
  const int row = blockIdx.x, tid = threadIdx.x;
  const size_t base = (size_t)row * HD + tid * 16;
  float v[16];
#pragma unroll
  for (int j = 0; j < 4; ++j) ((float4*)v)[j] = ((const float4*)(resid + base))[j];
  float ss = 0.0f;
#pragma unroll
  for (int j = 0; j < 16; ++j) ss += v[j] * v[j];
  float tot = block_sum256(ss);
  float rs = 1.0f / sqrtf(tot * (1.0f / HD) + 1e-6f);
  const float* nwp = nw + (size_t)li * HD + tid * 16;
  float y[16];
#pragma unroll
  for (int j = 0; j < 16; ++j) y[j] = v[j] * rs * nwp[j];
  quant_store16(y, agp[li], yq + base);
}

__global__ __launch_bounds__(256) void k_final_norm(
    float* __restrict__ io, const float* __restrict__ nw) {
  const int row = blockIdx.x, tid = threadIdx.x;
  const size_t base = (size_t)row * HD + tid * 16;
  float v[16];
#pragma unroll
  for (int j = 0; j < 4; ++j) ((float4*)v)[j] = ((const float4*)(io + base))[j];
  float ss = 0.0f;
#pragma unroll
  for (int j = 0; j < 16; ++j) ss += v[j] * v[j];
  float tot = block_sum256(ss);
  float rs = 1.0f / sqrtf(tot * (1.0f / HD) + 1e-6f);
  const float* nwp = nw + (size_t)3 * HD + tid * 16;
#pragma unroll
  for (int j = 0; j < 16; ++j) v[j] = v[j] * rs * nwp[j];
#pragma unroll
  for (int j = 0; j < 4; ++j) ((float4*)(io + base))[j] = ((float4*)v)[j];
}

__global__ __launch_bounds__(256) void k_quant_w(
    const float* __restrict__ w, const float* __restrict__ wgp, int li,
    u16* __restrict__ wq) {
  const int row = blockIdx.x, tid = threadIdx.x;
  const size_t base = (size_t)li * HD * HD + (size_t)row * HD + tid * 16;
  float v[16];
#pragma unroll
  for (int j = 0; j < 4; ++j) ((float4*)v)[j] = ((const float4*)(w + base))[j];
  quant_store16(v, wgp[li], wq + (size_t)row * HD + tid * 16);
}

// ---------- bf16 GEMM (m97 structure): z = A @ B^T, resid += z*alpha ----------
// A [TD, HD] bf16 bits, B [HD, HD] bf16 bits. 128x128 tile, BK=32, 4 waves,
// each wave 64x64 = 4x4 mfma_f32_16x16x32_bf16 tiles.

__global__ __launch_bounds__(256) void k_gemm(
    const u16* __restrict__ A, const u16* __restrict__ B,
    float* __restrict__ resid, const float* __restrict__ agp,
    const float* __restrict__ wgp, int layer) {
  __shared__ __align__(16) u16 ldsA[128 * 32];
  __shared__ __align__(16) u16 ldsB[128 * 32];
  const int tid = threadIdx.x;
  const int wave = tid >> 6, lane = tid & 63;
  const int m0 = blockIdx.y * 128, n0 = blockIdx.x * 128;

  // staging: tile is 128 rows x 32 cols bf16 = 512 chunks of 16B, row-major.
  // chunk c -> row c/4, col (c&3)*8; lds byte offset c*16 (lane-contiguous).
  const int c0 = wave * 64 + lane;
  const int c1 = c0 + 256;
  const int rA0 = c0 >> 2, col0 = (c0 & 3) * 8;
  const int rA1 = c1 >> 2, col1 = (c1 & 3) * 8;

  const u16* gA0 = A + (size_t)(m0 + rA0) * HD + col0;
  const u16* gA1 = A + (size_t)(m0 + rA1) * HD + col1;
  const u16* gB0 = B + (size_t)(n0 + rA0) * HD + col0;
  const u16* gB1 = B + (size_t)(n0 + rA1) * HD + col1;
  u16* lA0 = ldsA + c0 * 8;
  u16* lA1 = ldsA + c1 * 8;
  u16* lB0 = ldsB + c0 * 8;
  u16* lB1 = ldsB + c1 * 8;

  const int wm = (wave >> 1) * 64, wn = (wave & 1) * 64;
  const int r = lane & 15, q = lane >> 4;

  f32x4 acc[4][4];
#pragma unroll
  for (int i = 0; i < 4; ++i)
#pragma unroll
    for (int j = 0; j < 4; ++j) acc[i][j] = (f32x4){0.f, 0.f, 0.f, 0.f};

  for (int k0 = 0; k0 < HD; k0 += 32) {
    __syncthreads();  // protect LDS from previous iteration's reads
    GL16(gA0, lA0);
    GL16(gA1, lA1);
    GL16(gB0, lB0);
    GL16(gB1, lB1);
    gA0 += 32; gA1 += 32; gB0 += 32; gB1 += 32;
    __syncthreads();  // staging complete (vmcnt drained by barrier)
    bf16x8 a[4], b[4];
#pragma unroll
    for (int i = 0; i < 4; ++i)
      a[i] = *(const bf16x8*)&ldsA[(wm + i * 16 + r) * 32 + q * 8];
#pragma unroll
    for (int j = 0; j < 4; ++j)
      b[j] = *(const bf16x8*)&ldsB[(wn + j * 16 + r) * 32 + q * 8];
#pragma unroll
    for (int i = 0; i < 4; ++i)
#pragma unroll
      for (int j = 0; j < 4; ++j)
        acc[i][j] = __builtin_amdgcn_mfma_f32_16x16x32_bf16(a[i], b[j], acc[i][j], 0, 0, 0);
  }

  const float alpha = 1.0f / (agp[layer] * wgp[layer]);
  // C/D layout: col = lane&15 (n), row = (lane>>4)*4 + reg (m)
#pragma unroll
  for (int i = 0; i < 4; ++i) {
    const int gm0 = m0 + wm + i * 16 + q * 4;
#pragma unroll
    for (int j = 0; j < 4; ++j) {
      const int gn = n0 + wn + j * 16 + r;
#pragma unroll
      for (int t = 0; t < 4; ++t) {
        float* p = resid + (size_t)(gm0 + t) * HD + gn;
        *p = fmaf(acc[i][j][t], alpha, *p);
      }
    }
  }
}

// ---------- host ----------

extern "C" void kernel_launch(void* const* d_in, const int* in_sizes, int n_in,
                              void* d_out, int out_size, void* d_ws, size_t ws_size,
                              hipStream_t stream) {
  const float* hs = (const float*)d_in[0];
  const float* nw = (const float*)d_in[1];
  const float* w = (const float*)d_in[2];
  const float* ag = (const float*)d_in[3];
  const float* wg = (const float*)d_in[4];
  float* out = (float*)d_out;  // fp32 resid scratch; final y overwrites in place

  u16* wq = (u16*)d_ws;                    // HD*HD bf16 bits (32 MiB), reused per layer
  u16* yq = (u16*)d_ws + (size_t)HD * HD;  // TD*HD bf16 bits (64 MiB)

  k_relu_norm_quant<<<TD, 256, 0, stream>>>(hs, nw, ag, out, yq);
  for (int l = 0; l < 3; ++l) {
    k_quant_w<<<HD, 256, 0, stream>>>(w, wg, l, wq);
    k_gemm<<<dim3(HD / 128, TD / 128), 256, 0, stream>>>(yq, wq, out, ag, wg, l);
    if (l < 2) k_norm_quant<<<TD, 256, 0, stream>>>(out, nw, ag, l + 1, yq);
  }
  k_final_norm<<<TD, 256, 0, stream>>>(out, nw);
}

// Round 2
// 1509.338 us; speedup vs baseline: 1.1014x; 1.1014x over previous
//
#include <hip/hip_runtime.h>
#include <stdint.h>

#define HD 4096
#define TD 8192

typedef unsigned short u16;
typedef unsigned int u32;
typedef __bf16 bf16x8 __attribute__((ext_vector_type(8)));
typedef float f32x4 __attribute__((ext_vector_type(4)));

// async global->LDS, 16B per lane; LDS dest is wave-uniform base + lane*16,
// so lane l's global chunk must map to ldsbase + l*16 (layouts below do).
#define GL16(gp, lp) __builtin_amdgcn_global_load_lds( \
    (__attribute__((address_space(1))) void*)(void*)(uintptr_t)(gp), \
    (__attribute__((address_space(3))) void*)(lp), 16, 0, 0)

// ---------- NVFP4 quantization helpers ----------

// Round f (>=0) to nearest e4m3fn value (RTNE), returned as the decoded float.
__device__ __forceinline__ float e4m3_rtne(float f) {
  if (f <= 0.0f) return 0.0f;
  unsigned u = __float_as_uint(f);
  int e = (int)((u >> 23) & 0xff) - 127;
  if (e < -6) e = -6;
  float C = __uint_as_float((unsigned)(e + 147) << 23);  // 2^(e+20)
  float r = (f + C) - C;
  return fminf(r, 448.0f);
}

// Quantize 16 fp32 values (one NVFP4 block) with global scale g; write 16
// dequantized (q*s8 = dequant*g) values as bf16 bits (exact: <=6 sig bits).
__device__ __forceinline__ void quant_store16(const float v[16], float g, u16* dst) {
  float amax = 0.0f;
#pragma unroll
  for (int j = 0; j < 16; ++j) amax = fmaxf(amax, fabsf(v[j]));
  float s = e4m3_rtne(amax * g / 6.0f);
  u32 out[8];
  if (s > 0.0f) {
    const float m1 = 0.25f * s, m2 = 0.75f * s, m3 = 1.25f * s, m4 = 1.75f * s;
    const float m5 = 2.5f * s, m6 = 3.5f * s, m7 = 5.0f * s;
#pragma unroll
    for (int p = 0; p < 8; ++p) {
      u16 b[2];
#pragma unroll
      for (int h = 0; h < 2; ++h) {
        float t = v[2 * p + h] * g;
        float u = fabsf(t);
        float q = (u < m4) ? ((u < m2) ? ((u < m1) ? 0.0f : 0.5f)
                                       : ((u < m3) ? 1.0f : 1.5f))
                           : ((u < m6) ? ((u < m5) ? 2.0f : 3.0f)
                                       : ((u < m7) ? 4.0f : 6.0f));
        float val = copysignf(q * s, t);
        b[h] = (u16)(__float_as_uint(val) >> 16);  // exact bf16 truncation
      }
      out[p] = (u32)b[0] | ((u32)b[1] << 16);
    }
  } else {
#pragma unroll
    for (int p = 0; p < 8; ++p) out[p] = 0u;
  }
  uint4* d4 = (uint4*)dst;
  d4[0] = make_uint4(out[0], out[1], out[2], out[3]);
  d4[1] = make_uint4(out[4], out[5], out[6], out[7]);
}

__device__ __forceinline__ float block_sum256(float v) {
#pragma unroll
  for (int off = 32; off > 0; off >>= 1) v += __shfl_down(v, off, 64);
  __shared__ float red[4];
  int tid = threadIdx.x;
  if ((tid & 63) == 0) red[tid >> 6] = v;
  __syncthreads();
  return (red[0] + red[1]) + (red[2] + red[3]);
}

// ---------- elementwise / norm kernels (one block per row, 16 elem/thread) ----------

__global__ __launch_bounds__(256) void k_relu_norm_quant(
    const float* __restrict__ hs, const float* __restrict__ nw,
    const float* __restrict__ agp, float* __restrict__ resid,
    u16* __restrict__ yq) {
  const int row = blockIdx.x, tid = threadIdx.x;
  const size_t base = (size_t)row * HD + tid * 16;
  float v[16];
#pragma unroll
  for (int j = 0; j < 4; ++j) ((float4*)v)[j] = ((const float4*)(hs + base))[j];
  float ss = 0.0f;
#pragma unroll
  for (int j = 0; j < 16; ++j) {
    v[j] = fmaxf(v[j], 0.0f);
    ss += v[j] * v[j];
  }
#pragma unroll
  for (int j = 0; j < 4; ++j) ((float4*)(resid + base))[j] = ((float4*)v)[j];
  float tot = block_sum256(ss);
  float rs = 1.0f / sqrtf(tot * (1.0f / HD) + 1e-6f);
  const float* nwp = nw + tid * 16;  // norm_w[0]
  float y[16];
#pragma unroll
  for (int j = 0; j < 16; ++j) y[j] = v[j] * rs * nwp[j];
  quant_store16(y, agp[0], yq + base);
}

__global__ __launch_bounds__(256) void k_norm_quant(
    const float* __restrict__ resid, const float* __restrict__ nw,
    const float* __restrict__ agp, int li, u16* __restrict__ yq) {
  const int row = blockIdx.x, tid = threadIdx.x;
  const size_t base = (size_t)row * HD + tid * 16;
  float v[16];
#pragma unroll
  for (int j = 0; j < 4; ++j) ((float4*)v)[j] = ((const float4*)(resid + base))[j];
  float ss = 0.0f;
#pragma unroll
  for (int j = 0; j < 16; ++j) ss += v[j] * v[j];
  float tot = block_sum256(ss);
  float rs = 1.0f / sqrtf(tot * (1.0f / HD) + 1e-6f);
  const float* nwp = nw + (size_t)li * HD + tid * 16;
  float y[16];
#pragma unroll
  for (int j = 0; j < 16; ++j) y[j] = v[j] * rs * nwp[j];
  quant_store16(y, agp[li], yq + base);
}

__global__ __launch_bounds__(256) void k_final_norm(
    float* __restrict__ io, const float* __restrict__ nw) {
  const int row = blockIdx.x, tid = threadIdx.x;
  const size_t base = (size_t)row * HD + tid * 16;
  float v[16];
#pragma unroll
  for (int j = 0; j < 4; ++j) ((float4*)v)[j] = ((const float4*)(io + base))[j];
  float ss = 0.0f;
#pragma unroll
  for (int j = 0; j < 16; ++j) ss += v[j] * v[j];
  float tot = block_sum256(ss);
  float rs = 1.0f / sqrtf(tot * (1.0f / HD) + 1e-6f);
  const float* nwp = nw + (size_t)3 * HD + tid * 16;
#pragma unroll
  for (int j = 0; j < 16; ++j) v[j] = v[j] * rs * nwp[j];
#pragma unroll
  for (int j = 0; j < 4; ++j) ((float4*)(io + base))[j] = ((float4*)v)[j];
}

__global__ __launch_bounds__(256) void k_quant_w(
    const float* __restrict__ w, const float* __restrict__ wgp, int li,
    u16* __restrict__ wq) {
  const int row = blockIdx.x, tid = threadIdx.x;
  const size_t base = (size_t)li * HD * HD + (size_t)row * HD + tid * 16;
  float v[16];
#pragma unroll
  for (int j = 0; j < 4; ++j) ((float4*)v)[j] = ((const float4*)(w + base))[j];
  quant_store16(v, wgp[li], wq + (size_t)row * HD + tid * 16);
}

// ---------- bf16 GEMM (m97 structure): z = A @ B^T, resid += z*alpha ----------
// A [TD, HD] bf16 bits, B [HD, HD] bf16 bits. 128x128 tile, BK=32, 4 waves,
// each wave 64x64 = 4x4 mfma_f32_16x16x32_bf16 tiles.
//
// LDS layout is XOR-swizzled to kill ds_read_b128 bank conflicts while
// keeping the global_load_lds staging lane-contiguous:
//   row m's k-chunk kc (16B) lives at LDS chunk  m*4 + (kc ^ ((m>>1)&3)).
// Read side: chunkcol = q ^ ((r>>1)&3) -> each 8-lane LDS phase touches all
// 8 chunk-columns exactly once (conflict-free; was 4-way per phase).

__global__ __launch_bounds__(256, 5) void k_gemm(
    const u16* __restrict__ A, const u16* __restrict__ B,
    float* __restrict__ resid, const float* __restrict__ agp,
    const float* __restrict__ wgp, int layer) {
  __shared__ __align__(16) u16 ldsA[128 * 32];
  __shared__ __align__(16) u16 ldsB[128 * 32];
  const int tid = threadIdx.x;
  const int wave = tid >> 6, lane = tid & 63;
  const int m0 = blockIdx.y * 128, n0 = blockIdx.x * 128;

  // staging: lds chunk c <- global (row = c>>2, kchunk = (c&3) ^ ((c>>3)&3))
  const int c0 = wave * 64 + lane;
  const int c1 = c0 + 256;
  const int rA0 = c0 >> 2, col0 = ((c0 & 3) ^ ((c0 >> 3) & 3)) * 8;
  const int rA1 = c1 >> 2, col1 = ((c1 & 3) ^ ((c1 >> 3) & 3)) * 8;

  const u16* gA0 = A + (size_t)(m0 + rA0) * HD + col0;
  const u16* gA1 = A + (size_t)(m0 + rA1) * HD + col1;
  const u16* gB0 = B + (size_t)(n0 + rA0) * HD + col0;
  const u16* gB1 = B + (size_t)(n0 + rA1) * HD + col1;
  u16* lA0 = ldsA + c0 * 8;
  u16* lA1 = ldsA + c1 * 8;
  u16* lB0 = ldsB + c0 * 8;
  u16* lB1 = ldsB + c1 * 8;

  const int wm = (wave >> 1) * 64, wn = (wave & 1) * 64;
  const int r = lane & 15, q = lane >> 4;
  // swizzled k-chunk column for fragment reads (row bits 1..2 == r bits 1..2)
  const int sw = (q ^ ((r >> 1) & 3)) * 8;

  f32x4 acc[4][4];
#pragma unroll
  for (int i = 0; i < 4; ++i)
#pragma unroll
    for (int j = 0; j < 4; ++j) acc[i][j] = (f32x4){0.f, 0.f, 0.f, 0.f};

  for (int k0 = 0; k0 < HD; k0 += 32) {
    __syncthreads();  // protect LDS from previous iteration's reads
    GL16(gA0, lA0);
    GL16(gA1, lA1);
    GL16(gB0, lB0);
    GL16(gB1, lB1);
    gA0 += 32; gA1 += 32; gB0 += 32; gB1 += 32;
    __syncthreads();  // staging complete (vmcnt drained by barrier)
    bf16x8 a[4], b[4];
#pragma unroll
    for (int i = 0; i < 4; ++i)
      a[i] = *(const bf16x8*)&ldsA[(wm + i * 16 + r) * 32 + sw];
#pragma unroll
    for (int j = 0; j < 4; ++j)
      b[j] = *(const bf16x8*)&ldsB[(wn + j * 16 + r) * 32 + sw];
#pragma unroll
    for (int i = 0; i < 4; ++i)
#pragma unroll
      for (int j = 0; j < 4; ++j)
        acc[i][j] = __builtin_amdgcn_mfma_f32_16x16x32_bf16(a[i], b[j], acc[i][j], 0, 0, 0);
  }

  const float alpha = 1.0f / (agp[layer] * wgp[layer]);
  // C/D layout: col = lane&15 (n), row = (lane>>4)*4 + reg (m)
#pragma unroll
  for (int i = 0; i < 4; ++i) {
    const int gm0 = m0 + wm + i * 16 + q * 4;
#pragma unroll
    for (int j = 0; j < 4; ++j) {
      const int gn = n0 + wn + j * 16 + r;
#pragma unroll
      for (int t = 0; t < 4; ++t) {
        float* p = resid + (size_t)(gm0 + t) * HD + gn;
        *p = fmaf(acc[i][j][t], alpha, *p);
      }
    }
  }
}

// ---------- host ----------

extern "C" void kernel_launch(void* const* d_in, const int* in_sizes, int n_in,
                              void* d_out, int out_size, void* d_ws, size_t ws_size,
                              hipStream_t stream) {
  const float* hs = (const float*)d_in[0];
  const float* nw = (const float*)d_in[1];
  const float* w = (const float*)d_in[2];
  const float* ag = (const float*)d_in[3];
  const float* wg = (const float*)d_in[4];
  float* out = (float*)d_out;  // fp32 resid scratch; final y overwrites in place

  u16* wq = (u16*)d_ws;                    // HD*HD bf16 bits (32 MiB), reused per layer
  u16* yq = (u16*)d_ws + (size_t)HD * HD;  // TD*HD bf16 bits (64 MiB)

  k_relu_norm_quant<<<TD, 256, 0, stream>>>(hs, nw, ag, out, yq);
  for (int l = 0; l < 3; ++l) {
    k_quant_w<<<HD, 256, 0, stream>>>(w, wg, l, wq);
    k_gemm<<<dim3(HD / 128, TD / 128), 256, 0, stream>>>(yq, wq, out, ag, wg, l);
    if (l < 2) k_norm_quant<<<TD, 256, 0, stream>>>(out, nw, ag, l + 1, yq);
  }
  k_final_norm<<<TD, 256, 0, stream>>>(out, nw);
}